// Round 23
// baseline (2568.299 us; speedup 1.0000x reference)
//
#include <hip/hip_runtime.h>
#include <hip/hip_bf16.h>

// Problem constants
#define B_ 4
#define S_ 2048
#define E_ 2048
#define H_ 16
#define D_ 128
#define M_ (B_*S_)   // 8192 rows

typedef __attribute__((ext_vector_type(8))) short short8;
typedef __attribute__((ext_vector_type(4))) float f32x4;

__device__ __forceinline__ unsigned short f2bf(float f) {
  union { __hip_bfloat16 h; unsigned short u; } c;
  c.h = __float2bfloat16(f);
  return c.u;
}

__device__ __forceinline__ void gld_lds16(const void* g, void* l) {
  __builtin_amdgcn_global_load_lds((const __attribute__((address_space(1))) void*)g,
                                   (__attribute__((address_space(3))) void*)l, 16, 0, 0);
}

// bare HW exp2: one v_exp_f32
__device__ __forceinline__ float fexp2(float x) {
#if __has_builtin(__builtin_amdgcn_exp2f)
  return __builtin_amdgcn_exp2f(x);
#else
  return exp2f(x);
#endif
}

// ---------------- fp32 -> bf16 cast (vectorized) ----------------
__global__ __launch_bounds__(256) void cast_bf16_kernel(const float* __restrict__ in,
                                                        unsigned short* __restrict__ out,
                                                        int n4) {
  int i = blockIdx.x * 256 + threadIdx.x;
  if (i >= n4) return;
  float4 v = ((const float4*)in)[i];
  ushort4 o;
  o.x = f2bf(v.x); o.y = f2bf(v.y); o.z = f2bf(v.z); o.w = f2bf(v.w);
  ((ushort4*)out)[i] = o;
}

// 4 weight casts in one launch: blockIdx.y selects the matrix.
__global__ __launch_bounds__(256) void cast_w4_kernel(const float* __restrict__ w0,
                                                      const float* __restrict__ w1,
                                                      const float* __restrict__ w2,
                                                      const float* __restrict__ w3,
                                                      unsigned short* __restrict__ o0,
                                                      unsigned short* __restrict__ o1,
                                                      unsigned short* __restrict__ o2,
                                                      unsigned short* __restrict__ o3,
                                                      int n4) {
  int i = blockIdx.x * 256 + threadIdx.x;
  if (i >= n4) return;
  const float* in = (blockIdx.y == 0) ? w0 : (blockIdx.y == 1) ? w1 : (blockIdx.y == 2) ? w2 : w3;
  unsigned short* out = (blockIdx.y == 0) ? o0 : (blockIdx.y == 1) ? o1 : (blockIdx.y == 2) ? o2 : o3;
  float4 v = ((const float4*)in)[i];
  ushort4 o;
  o.x = f2bf(v.x); o.y = f2bf(v.y); o.z = f2bf(v.z); o.w = f2bf(v.w);
  ((ushort4*)out)[i] = o;
}

// ---------------- GEMM core: r14 one-barrier flow at BK=32 (r23: 2 blocks/CU) ----------------
// 256x256 tile, BK=32, 512 thr (8 waves, 2M x 4N), DOUBLE-BUFFERED LDS,
// ONE barrier per K-tile (T3-minimum, r14-verified flow):
//   prologue: stage tile0 -> buf0 (4 gld_lds)
//   iter t:   __syncthreads()          // vmcnt+lgkm drain: buf[t&1] staged;
//                                      // all waves' reads of buf^1 finished
//             issue stage(t+1)->buf^1  // lands under the 32-MFMA compute
//             compute tile t from buf[t&1]
// LDS: As/Bs each 2 x 16 KB -> 64 KB total -> TWO blocks/CU (16 waves/CU).
// Mechanism (r22 post-mortem): at 1 block/CU the barrier drain stalls the
// whole CU (MfmaUtil 40%, FETCH halving changed nothing -> schedule-bound);
// with 2 co-resident blocks the drains interleave with the other block's
// MFMA (m114 co-scheduling) — the same TLP that makes flash_attn efficient.
// NOT the failed r15/r20 structure (those were 1 block/CU + 4-buffer depth).
// Buffer audit: max byte = 16384 + 8192 + 7168 + 1008 = 32752 < 32768.
//
// LDS tile [256][32] bf16 (64 B rows), swizzle u ^= (row>>1)&3 on the GLOBAL
// source (linear LDS dest, rule 21); staging issues step rows by 128
// (128>>1=64, &3==0 -> per-thread constant); read row = wr+mh*64+i*16+lr
// with wr,64,16 all (x>>1)&3==0 -> (row>>1)&3 = (lr>>1)&3. 2-way reads
// (free, m136). Geometry correctness-proven in r15/r20 (both passed).
// TR=true: C^T via swapped-operand MFMA (m89-swapped epilogue).
template <typename OutT, bool TR>
__device__ __forceinline__ void gemm_core(const unsigned short* __restrict__ A,
                                          const unsigned short* __restrict__ W,
                                          const float* __restrict__ bias,
                                          OutT* __restrict__ C,
                                          int M, int N, int K, float oscale,
                                          int m0, int n0,
                                          unsigned short* As, unsigned short* Bs) {
  const int tid  = threadIdx.x;
  const int lane = tid & 63;
  const int wid  = tid >> 6;          // 0..7
  const int wr = (wid >> 2) * 128;    // wave row offset in tile (2 M-waves)
  const int wc = (wid & 3) * 64;      // wave col offset in tile (4 N-waves)
  const int lr  = lane & 15;
  const int lg  = lane >> 4;

  f32x4 acc[8][4];
#pragma unroll
  for (int i = 0; i < 8; i++)
#pragma unroll
    for (int j = 0; j < 4; j++) acc[i][j] = (f32x4){0.f, 0.f, 0.f, 0.f};

  // staging: 2 issues/operand per K-tile (512 thr x 16 B = 8 KB = 128 rows x 64 B)
  const int rSt = tid >> 2;                       // 0..127
  const int uSt = (tid & 3) ^ ((rSt >> 1) & 3);   // pre-swizzled 16B unit
  const unsigned short* asrc = A + (size_t)(m0 + rSt) * K + uSt * 8;
  const unsigned short* bsrc = W + (size_t)(n0 + rSt) * K + uSt * 8;
  char* adst = (char*)As + wid * 1024;            // + buf*16384 + issue*8192
  char* bdst = (char*)Bs + wid * 1024;
  const size_t rowK128 = (size_t)128 * K;

  const int cbq = ((lg ^ ((lr >> 1) & 3)) << 4);  // read byte-col (swizzled)
  const int nK = K >> 5;                          // 64 K-tiles of 32

  // prologue: stage tile 0 into buf 0
  gld_lds16(asrc,           adst);
  gld_lds16(asrc + rowK128, adst + 8192);
  gld_lds16(bsrc,           bdst);
  gld_lds16(bsrc + rowK128, bdst + 8192);

  for (int t = 0; t < nK; ++t) {
    const int bo = (t & 1) * 16384;         // byte offset of current buffer
    __syncthreads();   // vmcnt+lgkm drain: buf staged; buf^1 reads all done

    if (t + 1 < nK) {
      const size_t ko = (size_t)(t + 1) << 5;
      const int nbo = bo ^ 16384;
      gld_lds16(asrc + ko,           adst + nbo);
      gld_lds16(asrc + ko + rowK128, adst + nbo + 8192);
      gld_lds16(bsrc + ko,           bdst + nbo);
      gld_lds16(bsrc + ko + rowK128, bdst + nbo + 8192);
    }

    // compute tile t: 2 m-halves x 16 MFMA (32 MFMA/wave)
    const char* AsB = (const char*)As + bo;
    const char* BsB = (const char*)Bs + bo;
    short8 bf[4];
#pragma unroll
    for (int j = 0; j < 4; j++)
      bf[j] = *(const short8*)(BsB + (wc + j * 16 + lr) * 64 + cbq);
#pragma unroll
    for (int mh = 0; mh < 2; mh++) {
      short8 af[4];
#pragma unroll
      for (int i = 0; i < 4; i++)
        af[i] = *(const short8*)(AsB + (wr + mh * 64 + i * 16 + lr) * 64 + cbq);
      __builtin_amdgcn_s_setprio(1);
#pragma unroll
      for (int i = 0; i < 4; i++)
#pragma unroll
        for (int j = 0; j < 4; j++) {
          if constexpr (TR)
            acc[mh * 4 + i][j] = __builtin_amdgcn_mfma_f32_16x16x32_bf16(bf[j], af[i], acc[mh * 4 + i][j], 0, 0, 0);
          else
            acc[mh * 4 + i][j] = __builtin_amdgcn_mfma_f32_16x16x32_bf16(af[i], bf[j], acc[mh * 4 + i][j], 0, 0, 0);
        }
      __builtin_amdgcn_s_setprio(0);
    }
  }

  if constexpr (TR) {
    // C^T epilogue: D[n][m], n = wc+j*16+lg*4+r, m = wr+i*16+lr  [swapped m89]
    const int lg4 = lg * 4;
#pragma unroll
    for (int j = 0; j < 4; j++) {
      const int gn = n0 + wc + j * 16 + lg4;
      const float4 bv4 = *(const float4*)&bias[gn];
#pragma unroll
      for (int i = 0; i < 8; i++) {
        const int gm = m0 + wr + i * 16 + lr;
#pragma unroll
        for (int r = 0; r < 4; r++) {
          const float v = (acc[i][j][r] + ((const float*)&bv4)[r]) * oscale;
          ((unsigned short*)C)[(size_t)(gn + r) * M + gm] = f2bf(v);
        }
      }
    }
  } else {
    // epilogue: C/D layout col=lane&15, row=(lane>>4)*4+r  [m89-verified]
#pragma unroll
    for (int i = 0; i < 8; i++) {
      const int gm = m0 + wr + i * 16 + lg * 4;
#pragma unroll
      for (int j = 0; j < 4; j++) {
        const int gn = n0 + wc + j * 16 + lr;
        const float bv = bias[gn];
#pragma unroll
        for (int r = 0; r < 4; r++) {
          const float v = (acc[i][j][r] + bv) * oscale;
          if constexpr (sizeof(OutT) == 2)
            ((unsigned short*)C)[(size_t)(gm + r) * N + gn] = f2bf(v);
          else
            ((float*)C)[(size_t)(gm + r) * N + gn] = v;
        }
      }
    }
  }
}

// ---------------- standalone GEMM (used for the O-projection) ----------------
template <typename OutT, bool TR = false>
__global__ __launch_bounds__(512, 4) void gemm_bt256(const unsigned short* __restrict__ A,
                                                     const unsigned short* __restrict__ W,
                                                     const float* __restrict__ bias,
                                                     OutT* __restrict__ C,
                                                     int M, int N, int K, float oscale) {
  __shared__ unsigned short As[2 * 256 * 32];   // 2 x 16 KB
  __shared__ unsigned short Bs[2 * 256 * 32];   // 2 x 16 KB
  const int nwg = gridDim.x * gridDim.y;
  const int lin = blockIdx.x + gridDim.x * blockIdx.y;
  const int nl  = (lin & 7) * (nwg >> 3) + (lin >> 3);
  const int m0 = (nl / gridDim.x) * 256;
  const int n0 = (nl % gridDim.x) * 256;
  gemm_core<OutT, TR>(A, W, bias, C, M, N, K, oscale, m0, n0, As, Bs);
}

// ---------------- fused QKV GEMM, y-decoded (r22-verified) ----------------
// Grid (256, 3): blockIdx.y selects the weight (0=Q 1=K 2=V); blockIdx.x uses
// the standalone 256-block chunked swizzle (bijective).
__global__ __launch_bounds__(512, 4) void gemm_qkv(const unsigned short* __restrict__ A,
                                                   const unsigned short* __restrict__ Wq,
                                                   const unsigned short* __restrict__ Wk,
                                                   const unsigned short* __restrict__ Wv,
                                                   const float* __restrict__ bq,
                                                   const float* __restrict__ bk,
                                                   const float* __restrict__ bv,
                                                   unsigned short* __restrict__ Qo,
                                                   unsigned short* __restrict__ Ko,
                                                   unsigned short* __restrict__ VTo,
                                                   int M, int N, int K, float qs) {
  __shared__ unsigned short As[2 * 256 * 32];   // 2 x 16 KB
  __shared__ unsigned short Bs[2 * 256 * 32];   // 2 x 16 KB
  const int lin = blockIdx.x;                   // 0..255
  const int nl  = (lin & 7) * 32 + (lin >> 3);  // bijective on [0,256)
  const int m0  = (nl >> 3) * 256;              // 32 m-panels
  const int n0  = (nl & 7) * 256;               // 8 n-tiles
  const int wsel = blockIdx.y;                  // 0=Q 1=K 2=V (block-uniform)
  if (wsel == 0)
    gemm_core<unsigned short, false>(A, Wq, bq, Qo, M, N, K, qs,   m0, n0, As, Bs);
  else if (wsel == 1)
    gemm_core<unsigned short, false>(A, Wk, bk, Ko, M, N, K, 1.0f, m0, n0, As, Bs);
  else
    gemm_core<unsigned short, true >(A, Wv, bv, VTo, M, N, K, 1.0f, m0, n0, As, Bs);
}

// ---------------- causal flash attention (folded, swapped ops, dual-q, KVBLK=64) ----------------
// r18-verified, byte-identical. Each wave owns TWO 16-row q-groups (G0: rows
// qblk+wid*16, G1: +64) so every kf/vb LDS read feeds TWO MFMAs -> LDS bytes
// per MFMA halved. Block tile = 128 q rows; fold pairs tile bx with 15-bx ->
// 34 steps/block, balanced; grid 512 (2 blocks/CU). Staging r11-verified;
// log2-space softmax (fexp2) with defer-max; lazy lsum; masking: G0 diagonal
// at t==nt-2, inactive at t==nt-1; G1 diagonal at t==nt-1.
__global__ __launch_bounds__(256, 2) void flash_attn(const unsigned short* __restrict__ Q,
                                                     const unsigned short* __restrict__ K,
                                                     const unsigned short* __restrict__ VT,
                                                     unsigned short* __restrict__ Ctx) {
  __shared__ unsigned short Ks[64 * 128];    // 16 KB, swizzled K tile
  __shared__ unsigned short Vt[128 * 64];    // 16 KB, swizzled V^T tile
  __shared__ unsigned short Pl[4 * 2048];    // 16 KB, per-wave P feed (G0,G1)

  const int tid  = threadIdx.x;
  const int lane = tid & 63;
  const int wid  = tid >> 6;
  const int lr  = lane & 15;
  const int lg  = lane >> 4;
  const int lk8 = lg * 8;
  // ---- XCD-aware chunked swizzle of (q-pair, head, batch); 512 blocks ----
  const int lin = blockIdx.x + 8 * blockIdx.y + 128 * blockIdx.z;   // 0..511
  const int nl  = (lin & 7) * 64 + (lin >> 3);                      // bijective
  const int bxw = nl & 7;            // q-pair tile index (128-row tiles)
  const int h   = (nl >> 3) & 15;    // head
  const int b   = nl >> 7;           // batch (0..3)
  const size_t base = ((size_t)b * S_) * E_ + (size_t)h * D_;
  const unsigned short* __restrict__ Kh = K + base;
  // VT head base: row h*D+d, col b*S+kv
  const unsigned short* __restrict__ VTh = VT + (size_t)(h * D_) * M_ + (size_t)b * S_;
  unsigned short* Plf = Pl + wid * 2048;

  // ---- K staging geometry: tile 64x128 = 16 KB; 4 passes x 4096 B ----
  const int rK = tid >> 4;                  // 0..15
  const int cK = ((tid * 16) & 255) ^ ((rK & 7) << 4);
  const unsigned short* ksrcB = Kh + (size_t)rK * E_ + (cK >> 1);
  char* kdstB = (char*)Ks + wid * 1024;     // + p*4096

  // ---- V^T staging geometry: tile 128 d x 128 B = 16 KB; 4 passes ----
  const int dVb = tid >> 3;                 // 0..31
  const int cV  = tid & 7;
  const unsigned short* vsrcB = VTh + (size_t)dVb * M_ + (size_t)((cV ^ (dVb & 7)) * 8);
  char* vdstB = (char*)Vt + wid * 1024;     // + p*4096

  // ---- P feed addresses (per-lane, constant across steps) ----
  const int plw0 = (lg >> 1) * 128 + lr * 8 + (lg & 1) * 4;  // pack c at +c*256
  const int plrd = lg * 128 + lr * 8;                         // B-frag kk at +kk*512

#pragma unroll 1
  for (int half = 0; half < 2; ++half) {
    const int ti = half ? (15 - bxw) : bxw;
    const int qblk = ti * 128;              // q-tile base (128 rows)
    const int qrow0 = qblk + wid * 16 + lr; // G0 softmax row
    const int qrow1 = qrow0 + 64;           // G1 softmax row

    // ---- Q fragments for both groups (pre-scaled by log2e/sqrt(D)) ----
    short8 qf0[4], qf1[4];
#pragma unroll
    for (int kk = 0; kk < 4; kk++) {
      qf0[kk] = *(const short8*)&Q[base + (size_t)qrow0 * E_ + kk * 32 + lk8];
      qf1[kk] = *(const short8*)&Q[base + (size_t)qrow1 * E_ + kk * 32 + lk8];
    }

    f32x4 o0[8], o1[8];
#pragma unroll
    for (int d0 = 0; d0 < 8; d0++) {
      o0[d0] = (f32x4){0.f, 0.f, 0.f, 0.f};
      o1[d0] = (f32x4){0.f, 0.f, 0.f, 0.f};
    }
    float m0r = -INFINITY, m1r = -INFINITY;
    float l0 = 0.f, l1 = 0.f;               // per-lane partials (lazy reduce)

    const int nt = 2 * ti + 2;              // steps of 64 kv

    for (int t = 0; t < nt; ++t) {
      const int kv0 = t * 64;
      const size_t koff = (size_t)kv0 * E_;

      // ---- stage K + V^T (8 async global_load_lds; zero staging VALU) ----
#pragma unroll
      for (int p = 0; p < 4; ++p) {
        gld_lds16(ksrcB + koff + (size_t)(16 * p) * E_, kdstB + p * 4096);
        gld_lds16(vsrcB + (size_t)(32 * p) * M_ + kv0,  vdstB + p * 4096);
      }
      __syncthreads();   // barrier drain: tile staged

      const bool g0act = (t < nt - 1);      // G0 done after its diagonal
      const bool mk0   = (t == nt - 2);     // G0 diagonal step
      const bool mk1   = (t == nt - 1);     // G1 diagonal step

      // ---- S^T = K Q^T : shared kf read feeds both groups ----
      f32x4 s0[4], s1[4];
#pragma unroll
      for (int c = 0; c < 4; c++) {
        s0[c] = (f32x4){0.f, 0.f, 0.f, 0.f};
        s1[c] = (f32x4){0.f, 0.f, 0.f, 0.f};
      }
      const int swK = (lr & 7) << 4;
      if (g0act) {
        __builtin_amdgcn_s_setprio(1);
#pragma unroll
        for (int kk = 0; kk < 4; kk++) {
          const int cb = (kk * 64 + lg * 16) ^ swK;
#pragma unroll
          for (int c = 0; c < 4; c++) {
            const short8 kf = *(const short8*)((const char*)Ks + (c * 16 + lr) * 256 + cb);
            s1[c] = __builtin_amdgcn_mfma_f32_16x16x32_bf16(kf, qf1[kk], s1[c], 0, 0, 0);
            s0[c] = __builtin_amdgcn_mfma_f32_16x16x32_bf16(kf, qf0[kk], s0[c], 0, 0, 0);
          }
        }
        __builtin_amdgcn_s_setprio(0);
      } else {
        __builtin_amdgcn_s_setprio(1);
#pragma unroll
        for (int kk = 0; kk < 4; kk++) {
          const int cb = (kk * 64 + lg * 16) ^ swK;
#pragma unroll
          for (int c = 0; c < 4; c++) {
            const short8 kf = *(const short8*)((const char*)Ks + (c * 16 + lr) * 256 + cb);
            s1[c] = __builtin_amdgcn_mfma_f32_16x16x32_bf16(kf, qf1[kk], s1[c], 0, 0, 0);
          }
        }
        __builtin_amdgcn_s_setprio(0);
      }

      // ======== G1 softmax (always active) ========
      {
        float v[4][4];
#pragma unroll
        for (int c = 0; c < 4; c++)
#pragma unroll
          for (int r = 0; r < 4; r++) v[c][r] = s1[c][r];
        if (mk1) {
#pragma unroll
          for (int c = 0; c < 4; c++) {
            const int kvq = kv0 + c * 16 + lg * 4;
#pragma unroll
            for (int r = 0; r < 4; r++)
              if (kvq + r > qrow1) v[c][r] = -INFINITY;
          }
        }
        float pm = fmaxf(fmaxf(fmaxf(v[0][0], v[0][1]), fmaxf(v[0][2], v[0][3])),
                         fmaxf(fmaxf(v[1][0], v[1][1]), fmaxf(v[1][2], v[1][3])));
        pm = fmaxf(pm, fmaxf(fmaxf(fmaxf(v[2][0], v[2][1]), fmaxf(v[2][2], v[2][3])),
                             fmaxf(fmaxf(v[3][0], v[3][1]), fmaxf(v[3][2], v[3][3]))));
        pm = fmaxf(pm, __shfl_xor(pm, 16));
        pm = fmaxf(pm, __shfl_xor(pm, 32));
        const float need = pm - m1r;
        if (!__all(need <= 8.f)) {
          const float mnew = fmaxf(m1r, pm);
          const float al = fexp2(m1r - mnew);
          l1 *= al;
#pragma unroll
          for (int d0 = 0; d0 < 8; ++d0) {
            f32x4 tt = o1[d0];
            tt[0] *= al; tt[1] *= al; tt[2] *= al; tt[3] *= al;
            o1[d0] = tt;
          }
          m1r = mnew;
        }
        ushort4 wpk[4];
        float ps = 0.f;
#pragma unroll
        for (int c = 0; c < 4; c++) {
          const float e0 = fexp2(v[c][0] - m1r);
          const float e1 = fexp2(v[c][1] - m1r);
          const float e2 = fexp2(v[c][2] - m1r);
          const float e3 = fexp2(v[c][3] - m1r);
          wpk[c].x = f2bf(e0); wpk[c].y = f2bf(e1);
          wpk[c].z = f2bf(e2); wpk[c].w = f2bf(e3);
          ps += (e0 + e1) + (e2 + e3);
        }
        l1 += ps;
#pragma unroll
        for (int c = 0; c < 4; c++)
          *(ushort4*)&Plf[1024 + plw0 + c * 256] = wpk[c];
      }

      // ======== G0 softmax (while active) ========
      if (g0act) {
        float v[4][4];
#pragma unroll
        for (int c = 0; c < 4; c++)
#pragma unroll
          for (int r = 0; r < 4; r++) v[c][r] = s0[c][r];
        if (mk0) {
#pragma unroll
          for (int c = 0; c < 4; c++) {
            const int kvq = kv0 + c * 16 + lg * 4;
#pragma unroll
            for (int r = 0; r < 4; r++)
              if (kvq + r > qrow0) v[c][r] = -INFINITY;
          }
        }
        float pm = fmaxf(fmaxf(fmaxf(v[0][0], v[0][1]), fmaxf(v[0][2], v[0][3])),
                         fmaxf(fmaxf(v[1][0], v[1][1]), fmaxf(v[1][2], v[1][3])));
        pm = fmaxf(pm, fmaxf(fmaxf(fmaxf(v[2][0], v[2][1]), fmaxf(v[2][2], v[2][3])),
                             fmaxf(fmaxf(v[3][0], v[3][1]), fmaxf(v[3][2], v[3][3]))));
        pm = fmaxf(pm, __shfl_xor(pm, 16));
        pm = fmaxf(pm, __shfl_xor(pm, 32));
        const float need = pm - m0r;
        if (!__all(need <= 8.f)) {
          const float mnew = fmaxf(m0r, pm);
          const float al = fexp2(m0r - mnew);
          l0 *= al;
#pragma unroll
          for (int d0 = 0; d0 < 8; ++d0) {
            f32x4 tt = o0[d0];
            tt[0] *= al; tt[1] *= al; tt[2] *= al; tt[3] *= al;
            o0[d0] = tt;
          }
          m0r = mnew;
        }
        ushort4 wpk[4];
        float ps = 0.f;
#pragma unroll
        for (int c = 0; c < 4; c++) {
          const float e0 = fexp2(v[c][0] - m0r);
          const float e1 = fexp2(v[c][1] - m0r);
          const float e2 = fexp2(v[c][2] - m0r);
          const float e3 = fexp2(v[c][3] - m0r);
          wpk[c].x = f2bf(e0); wpk[c].y = f2bf(e1);
          wpk[c].z = f2bf(e2); wpk[c].w = f2bf(e3);
          ps += (e0 + e1) + (e2 + e3);
        }
        l0 += ps;
#pragma unroll
        for (int c = 0; c < 4; c++)
          *(ushort4*)&Plf[plw0 + c * 256] = wpk[c];
      }

      // wave-local: drain Pl writes; fence scheduler (rule 18)
      asm volatile("s_waitcnt lgkmcnt(0)" ::: "memory");
      __builtin_amdgcn_sched_barrier(0);

      // ---- O^T += V^T P : shared vb read feeds both groups ----
      const short8 pb1a = *(const short8*)&Plf[1024 + plrd];
      const short8 pb1b = *(const short8*)&Plf[1024 + plrd + 512];
      const int d7 = lr & 7;
      if (g0act) {
        const short8 pb0a = *(const short8*)&Plf[plrd];
        const short8 pb0b = *(const short8*)&Plf[plrd + 512];
        __builtin_amdgcn_s_setprio(1);
#pragma unroll
        for (int d0 = 0; d0 < 8; ++d0) {
          const int d = d0 * 16 + lr;
          const short8 vb0 = *(const short8*)&Vt[d * 64 + ((lg ^ d7) << 3)];
          const short8 vb1 = *(const short8*)&Vt[d * 64 + (((4 + lg) ^ d7) << 3)];
          o1[d0] = __builtin_amdgcn_mfma_f32_16x16x32_bf16(vb0, pb1a, o1[d0], 0, 0, 0);
          o1[d0] = __builtin_amdgcn_mfma_f32_16x16x32_bf16(vb1, pb1b, o1[d0], 0, 0, 0);
          o0[d0] = __builtin_amdgcn_mfma_f32_16x16x32_bf16(vb0, pb0a, o0[d0], 0, 0, 0);
          o0[d0] = __builtin_amdgcn_mfma_f32_16x16x32_bf16(vb1, pb0b, o0[d0], 0, 0, 0);
        }
        __builtin_amdgcn_s_setprio(0);
      } else {
        __builtin_amdgcn_s_setprio(1);
#pragma unroll
        for (int d0 = 0; d0 < 8; ++d0) {
          const int d = d0 * 16 + lr;
          const short8 vb0 = *(const short8*)&Vt[d * 64 + ((lg ^ d7) << 3)];
          const short8 vb1 = *(const short8*)&Vt[d * 64 + (((4 + lg) ^ d7) << 3)];
          o1[d0] = __builtin_amdgcn_mfma_f32_16x16x32_bf16(vb0, pb1a, o1[d0], 0, 0, 0);
          o1[d0] = __builtin_amdgcn_mfma_f32_16x16x32_bf16(vb1, pb1b, o1[d0], 0, 0, 0);
        }
        __builtin_amdgcn_s_setprio(0);
      }
      __syncthreads();   // all Ks/Vt reads done before next staging
    }

    // ---- finalize lsums (lazy reduce) + store ctx for both groups ----
    float ls0 = l0, ls1 = l1;
    ls0 += __shfl_xor(ls0, 16); ls0 += __shfl_xor(ls0, 32);
    ls1 += __shfl_xor(ls1, 16); ls1 += __shfl_xor(ls1, 32);
    const float inv0 = 1.0f / ls0;
    const float inv1 = 1.0f / ls1;
    unsigned short* crow0 = Ctx + base + (size_t)qrow0 * E_ + lg * 4;
    unsigned short* crow1 = Ctx + base + (size_t)qrow1 * E_ + lg * 4;
#pragma unroll
    for (int d0 = 0; d0 < 8; ++d0) {
      ushort4 st0, st1;
      st0.x = f2bf(o0[d0][0] * inv0);
      st0.y = f2bf(o0[d0][1] * inv0);
      st0.z = f2bf(o0[d0][2] * inv0);
      st0.w = f2bf(o0[d0][3] * inv0);
      st1.x = f2bf(o1[d0][0] * inv1);
      st1.y = f2bf(o1[d0][1] * inv1);
      st1.z = f2bf(o1[d0][2] * inv1);
      st1.w = f2bf(o1[d0][3] * inv1);
      *(ushort4*)&crow0[d0 * 16] = st0;
      *(ushort4*)&crow1[d0 * 16] = st1;
    }
  }
}

// ---------------- launcher ----------------
extern "C" void kernel_launch(void* const* d_in, const int* in_sizes, int n_in,
                              void* d_out, int out_size, void* d_ws, size_t ws_size,
                              hipStream_t stream) {
  const float* x  = (const float*)d_in[0];
  // d_in[1] = causal_mask (tril) — implemented analytically
  const float* wq = (const float*)d_in[2];
  const float* bq = (const float*)d_in[3];
  const float* wk = (const float*)d_in[4];
  const float* bk = (const float*)d_in[5];
  const float* wv = (const float*)d_in[6];
  const float* bv = (const float*)d_in[7];
  const float* wo = (const float*)d_in[8];
  const float* bo = (const float*)d_in[9];
  float* out = (float*)d_out;

  char* ws = (char*)d_ws;
  const size_t MB = 1024 * 1024;
  unsigned short* xb  = (unsigned short*)(ws);             // 32 MB
  unsigned short* wqb = (unsigned short*)(ws + 32 * MB);   // 8 MB
  unsigned short* wkb = (unsigned short*)(ws + 40 * MB);   // 8 MB
  unsigned short* wvb = (unsigned short*)(ws + 48 * MB);   // 8 MB
  unsigned short* wob = (unsigned short*)(ws + 56 * MB);   // 8 MB
  unsigned short* Qb  = (unsigned short*)(ws + 64 * MB);   // 32 MB
  unsigned short* Kb  = (unsigned short*)(ws + 96 * MB);   // 32 MB
  unsigned short* VTb = (unsigned short*)(ws + 128 * MB);  // 32 MB, V^T [E][M]
  unsigned short* Cb  = (unsigned short*)(ws + 160 * MB);  // 32 MB -> 192 MB total

  const int nx4 = M_ * E_ / 4;   // x elements /4
  const int nw4 = E_ * E_ / 4;   // weight elements /4
  cast_bf16_kernel<<<nx4 / 256, 256, 0, stream>>>(x, xb, nx4);
  cast_w4_kernel<<<dim3(nw4 / 256, 4), 256, 0, stream>>>(wq, wk, wv, wo,
                                                         wqb, wkb, wvb, wob, nw4);

  // Q pre-scale: log2(e)/sqrt(D) -> attention works in log2-space (exp2 softmax)
  const float scale = 0.08838834764831845f * 1.44269504088896340736f;

  // fused Q/K/V projections, y-decoded: 256 x 3 blocks; 2 blocks/CU (r23)
  gemm_qkv<<<dim3(256, 3), 512, 0, stream>>>(xb, wqb, wkb, wvb, bq, bk, bv,
                                             Qb, Kb, VTb, M_, E_, E_, scale);

  // folded causal grid: block handles 128-row q-tiles bxw and 15-bxw (34 steps)
  flash_attn<<<dim3(S_ / 128 / 2, H_, B_), 256, 0, stream>>>(Qb, Kb, VTb, Cb);

  // O-projection
  gemm_bt256<float><<<dim3(E_ / 256, M_ / 256), 512, 0, stream>>>(Cb, wob, bo, out, M_, E_, E_, 1.0f);
}

// Round 24
// 396.956 us; speedup vs baseline: 6.4700x; 6.4700x over previous
//
#include <hip/hip_runtime.h>
#include <hip/hip_bf16.h>

// Problem constants
#define B_ 4
#define S_ 2048
#define E_ 2048
#define H_ 16
#define D_ 128
#define M_ (B_*S_)   // 8192 rows

typedef __attribute__((ext_vector_type(8))) short short8;
typedef __attribute__((ext_vector_type(4))) float f32x4;

__device__ __forceinline__ unsigned short f2bf(float f) {
  union { __hip_bfloat16 h; unsigned short u; } c;
  c.h = __float2bfloat16(f);
  return c.u;
}

__device__ __forceinline__ void gld_lds16(const void* g, void* l) {
  __builtin_amdgcn_global_load_lds((const __attribute__((address_space(1))) void*)g,
                                   (__attribute__((address_space(3))) void*)l, 16, 0, 0);
}

// bare HW exp2: one v_exp_f32
__device__ __forceinline__ float fexp2(float x) {
#if __has_builtin(__builtin_amdgcn_exp2f)
  return __builtin_amdgcn_exp2f(x);
#else
  return exp2f(x);
#endif
}

// ---------------- fp32 -> bf16 cast (vectorized) ----------------
__global__ __launch_bounds__(256) void cast_bf16_kernel(const float* __restrict__ in,
                                                        unsigned short* __restrict__ out,
                                                        int n4) {
  int i = blockIdx.x * 256 + threadIdx.x;
  if (i >= n4) return;
  float4 v = ((const float4*)in)[i];
  ushort4 o;
  o.x = f2bf(v.x); o.y = f2bf(v.y); o.z = f2bf(v.z); o.w = f2bf(v.w);
  ((ushort4*)out)[i] = o;
}

// 4 weight casts in one launch: blockIdx.y selects the matrix.
__global__ __launch_bounds__(256) void cast_w4_kernel(const float* __restrict__ w0,
                                                      const float* __restrict__ w1,
                                                      const float* __restrict__ w2,
                                                      const float* __restrict__ w3,
                                                      unsigned short* __restrict__ o0,
                                                      unsigned short* __restrict__ o1,
                                                      unsigned short* __restrict__ o2,
                                                      unsigned short* __restrict__ o3,
                                                      int n4) {
  int i = blockIdx.x * 256 + threadIdx.x;
  if (i >= n4) return;
  const float* in = (blockIdx.y == 0) ? w0 : (blockIdx.y == 1) ? w1 : (blockIdx.y == 2) ? w2 : w3;
  unsigned short* out = (blockIdx.y == 0) ? o0 : (blockIdx.y == 1) ? o1 : (blockIdx.y == 2) ? o2 : o3;
  float4 v = ((const float4*)in)[i];
  ushort4 o;
  o.x = f2bf(v.x); o.y = f2bf(v.y); o.z = f2bf(v.z); o.w = f2bf(v.w);
  ((ushort4*)out)[i] = o;
}

// ---------------- GEMM core (r14-verified pipeline) ----------------
// 256x256 tile, BK=64, 512 thr (8 waves, 2M x 4N), DOUBLE-BUFFERED LDS,
// ONE barrier per K-tile (T3-minimum):
//   prologue: stage tile0 -> buf0 (8 gld_lds)
//   iter t:   __syncthreads()          // vmcnt+lgkm drain: buf[t&1] staged;
//                                      // all waves' reads of buf^1 finished
//             issue stage(t+1)->buf^1  // lands under the 64-MFMA compute
//             compute tile t from buf[t&1]
// Buffer stride 32768 B (256 rows x 128 B); audit: 32768+3*8192+8191 < 65536.
// LDS tiles [256][64] bf16, XOR row-swizzle u ^= (row&7) on the GLOBAL source
// (linear LDS dest, rule 21) + same XOR on reads -> 2-way (free).
// TR=true: C^T via swapped-operand MFMA (m89-swapped epilogue).
// NOTE: counted-vmcnt/4-buffer variants regressed twice (r15, r20); the
// r23 BK=32 + __launch_bounds__(512,4) variant spilled acc to scratch
// (VGPR capped 104->64, 8.5 GB spill traffic) — default bounds are correct.
template <typename OutT, bool TR>
__device__ __forceinline__ void gemm_core(const unsigned short* __restrict__ A,
                                          const unsigned short* __restrict__ W,
                                          const float* __restrict__ bias,
                                          OutT* __restrict__ C,
                                          int M, int N, int K, float oscale,
                                          int m0, int n0,
                                          unsigned short* As, unsigned short* Bs) {
  const int tid  = threadIdx.x;
  const int lane = tid & 63;
  const int wid  = tid >> 6;          // 0..7
  const int wr = (wid >> 2) * 128;    // wave row offset in tile (2 M-waves)
  const int wc = (wid & 3) * 64;      // wave col offset in tile (4 N-waves)
  const int lr  = lane & 15;
  const int lg  = lane >> 4;

  f32x4 acc[8][4];
#pragma unroll
  for (int i = 0; i < 8; i++)
#pragma unroll
    for (int j = 0; j < 4; j++) acc[i][j] = (f32x4){0.f, 0.f, 0.f, 0.f};

  // staging: per issue 512 thr x 16 B = 8 KB = 64 rows x 128 B
  const int rS = tid >> 3;                  // 0..63
  const int uS = (tid & 7) ^ (rS & 7);      // issue-invariant swizzled unit
  const unsigned short* asrc = A + (size_t)(m0 + rS) * K + uS * 8;
  const unsigned short* bsrc = W + (size_t)(n0 + rS) * K + uS * 8;
  char* adst = (char*)As + wid * 1024;      // + buf*32768 + issue*8192
  char* bdst = (char*)Bs + wid * 1024;

  const int swR = (lr & 7) << 4;            // read-side XOR (row&7 == lr&7)
  const int nK = K >> 6;

  // prologue: stage tile 0 into buf 0
#pragma unroll
  for (int i = 0; i < 4; ++i) {
    gld_lds16(asrc + (size_t)(64 * i) * K, adst + i * 8192);
    gld_lds16(bsrc + (size_t)(64 * i) * K, bdst + i * 8192);
  }

  for (int t = 0; t < nK; ++t) {
    const int bo = (t & 1) * 32768;         // byte offset of current buffer
    __syncthreads();   // vmcnt+lgkm drain: buf staged; buf^1 reads all done

    if (t + 1 < nK) {
      const int kt2 = (t + 1) * 64;
      const int nbo = bo ^ 32768;
#pragma unroll
      for (int i = 0; i < 4; ++i) {
        gld_lds16(asrc + kt2 + (size_t)(64 * i) * K, adst + nbo + i * 8192);
        gld_lds16(bsrc + kt2 + (size_t)(64 * i) * K, bdst + nbo + i * 8192);
      }
    }

    // compute tile t: 2 k-slices x 2 m-halves x 16 MFMA
    const char* AsB = (const char*)As + bo;
    const char* BsB = (const char*)Bs + bo;
#pragma unroll
    for (int kk = 0; kk < 2; kk++) {
      const int cb = ((kk * 4 + lg) << 4) ^ swR;   // swizzled byte col
      short8 bf[4];
#pragma unroll
      for (int j = 0; j < 4; j++)
        bf[j] = *(const short8*)(BsB + (wc + j * 16 + lr) * 128 + cb);
#pragma unroll
      for (int mh = 0; mh < 2; mh++) {
        short8 af[4];
#pragma unroll
        for (int i = 0; i < 4; i++)
          af[i] = *(const short8*)(AsB + (wr + mh * 64 + i * 16 + lr) * 128 + cb);
        __builtin_amdgcn_s_setprio(1);
#pragma unroll
        for (int i = 0; i < 4; i++)
#pragma unroll
          for (int j = 0; j < 4; j++) {
            if constexpr (TR)
              acc[mh * 4 + i][j] = __builtin_amdgcn_mfma_f32_16x16x32_bf16(bf[j], af[i], acc[mh * 4 + i][j], 0, 0, 0);
            else
              acc[mh * 4 + i][j] = __builtin_amdgcn_mfma_f32_16x16x32_bf16(af[i], bf[j], acc[mh * 4 + i][j], 0, 0, 0);
          }
        __builtin_amdgcn_s_setprio(0);
      }
    }
  }

  if constexpr (TR) {
    // C^T epilogue: D[n][m], n = wc+j*16+lg*4+r, m = wr+i*16+lr  [swapped m89]
    const int lg4 = lg * 4;
#pragma unroll
    for (int j = 0; j < 4; j++) {
      const int gn = n0 + wc + j * 16 + lg4;
      const float4 bv4 = *(const float4*)&bias[gn];
#pragma unroll
      for (int i = 0; i < 8; i++) {
        const int gm = m0 + wr + i * 16 + lr;
#pragma unroll
        for (int r = 0; r < 4; r++) {
          const float v = (acc[i][j][r] + ((const float*)&bv4)[r]) * oscale;
          ((unsigned short*)C)[(size_t)(gn + r) * M + gm] = f2bf(v);
        }
      }
    }
  } else {
    // epilogue: C/D layout col=lane&15, row=(lane>>4)*4+r  [m89-verified]
#pragma unroll
    for (int i = 0; i < 8; i++) {
      const int gm = m0 + wr + i * 16 + lg * 4;
#pragma unroll
      for (int j = 0; j < 4; j++) {
        const int gn = n0 + wc + j * 16 + lr;
        const float bv = bias[gn];
#pragma unroll
        for (int r = 0; r < 4; r++) {
          const float v = (acc[i][j][r] + bv) * oscale;
          if constexpr (sizeof(OutT) == 2)
            ((unsigned short*)C)[(size_t)(gm + r) * N + gn] = f2bf(v);
          else
            ((float*)C)[(size_t)(gm + r) * N + gn] = v;
        }
      }
    }
  }
}

// ---------------- standalone GEMM (used for the O-projection) ----------------
template <typename OutT, bool TR = false>
__global__ __launch_bounds__(512) void gemm_bt256(const unsigned short* __restrict__ A,
                                                  const unsigned short* __restrict__ W,
                                                  const float* __restrict__ bias,
                                                  OutT* __restrict__ C,
                                                  int M, int N, int K, float oscale) {
  __shared__ unsigned short As[2 * 256 * 64];   // 2 x 32768 B
  __shared__ unsigned short Bs[2 * 256 * 64];   // 2 x 32768 B
  const int nwg = gridDim.x * gridDim.y;
  const int lin = blockIdx.x + gridDim.x * blockIdx.y;
  const int nl  = (lin & 7) * (nwg >> 3) + (lin >> 3);
  const int m0 = (nl / gridDim.x) * 256;
  const int n0 = (nl % gridDim.x) * 256;
  gemm_core<OutT, TR>(A, W, bias, C, M, N, K, oscale, m0, n0, As, Bs);
}

// ---------------- fused QKV GEMM, y-decoded (r22-verified) ----------------
// Grid (256, 3): blockIdx.y selects the weight (0=Q 1=K 2=V); blockIdx.x uses
// the standalone 256-block chunked swizzle -> per-GEMM panel locality
// identical to three separate launches, with no inter-launch serialization.
__global__ __launch_bounds__(512) void gemm_qkv(const unsigned short* __restrict__ A,
                                                const unsigned short* __restrict__ Wq,
                                                const unsigned short* __restrict__ Wk,
                                                const unsigned short* __restrict__ Wv,
                                                const float* __restrict__ bq,
                                                const float* __restrict__ bk,
                                                const float* __restrict__ bv,
                                                unsigned short* __restrict__ Qo,
                                                unsigned short* __restrict__ Ko,
                                                unsigned short* __restrict__ VTo,
                                                int M, int N, int K, float qs) {
  __shared__ unsigned short As[2 * 256 * 64];   // 2 x 32768 B
  __shared__ unsigned short Bs[2 * 256 * 64];   // 2 x 32768 B
  const int lin = blockIdx.x;                   // 0..255
  const int nl  = (lin & 7) * 32 + (lin >> 3);  // bijective on [0,256)
  const int m0  = (nl >> 3) * 256;              // 32 m-panels
  const int n0  = (nl & 7) * 256;               // 8 n-tiles
  const int wsel = blockIdx.y;                  // 0=Q 1=K 2=V (block-uniform)
  if (wsel == 0)
    gemm_core<unsigned short, false>(A, Wq, bq, Qo, M, N, K, qs,   m0, n0, As, Bs);
  else if (wsel == 1)
    gemm_core<unsigned short, false>(A, Wk, bk, Ko, M, N, K, 1.0f, m0, n0, As, Bs);
  else
    gemm_core<unsigned short, true >(A, Wv, bv, VTo, M, N, K, 1.0f, m0, n0, As, Bs);
}

// ---------------- causal flash attention (folded, swapped ops, dual-q, KVBLK=64) ----------------
// r18-verified, byte-identical. Each wave owns TWO 16-row q-groups (G0: rows
// qblk+wid*16, G1: +64) so every kf/vb LDS read feeds TWO MFMAs -> LDS bytes
// per MFMA halved. Block tile = 128 q rows; fold pairs tile bx with 15-bx ->
// 34 steps/block, balanced; grid 512 (2 blocks/CU). Staging r11-verified;
// log2-space softmax (fexp2) with defer-max; lazy lsum; masking: G0 diagonal
// at t==nt-2, inactive at t==nt-1; G1 diagonal at t==nt-1.
__global__ __launch_bounds__(256, 2) void flash_attn(const unsigned short* __restrict__ Q,
                                                     const unsigned short* __restrict__ K,
                                                     const unsigned short* __restrict__ VT,
                                                     unsigned short* __restrict__ Ctx) {
  __shared__ unsigned short Ks[64 * 128];    // 16 KB, swizzled K tile
  __shared__ unsigned short Vt[128 * 64];    // 16 KB, swizzled V^T tile
  __shared__ unsigned short Pl[4 * 2048];    // 16 KB, per-wave P feed (G0,G1)

  const int tid  = threadIdx.x;
  const int lane = tid & 63;
  const int wid  = tid >> 6;
  const int lr  = lane & 15;
  const int lg  = lane >> 4;
  const int lk8 = lg * 8;
  // ---- XCD-aware chunked swizzle of (q-pair, head, batch); 512 blocks ----
  const int lin = blockIdx.x + 8 * blockIdx.y + 128 * blockIdx.z;   // 0..511
  const int nl  = (lin & 7) * 64 + (lin >> 3);                      // bijective
  const int bxw = nl & 7;            // q-pair tile index (128-row tiles)
  const int h   = (nl >> 3) & 15;    // head
  const int b   = nl >> 7;           // batch (0..3)
  const size_t base = ((size_t)b * S_) * E_ + (size_t)h * D_;
  const unsigned short* __restrict__ Kh = K + base;
  // VT head base: row h*D+d, col b*S+kv
  const unsigned short* __restrict__ VTh = VT + (size_t)(h * D_) * M_ + (size_t)b * S_;
  unsigned short* Plf = Pl + wid * 2048;

  // ---- K staging geometry: tile 64x128 = 16 KB; 4 passes x 4096 B ----
  const int rK = tid >> 4;                  // 0..15
  const int cK = ((tid * 16) & 255) ^ ((rK & 7) << 4);
  const unsigned short* ksrcB = Kh + (size_t)rK * E_ + (cK >> 1);
  char* kdstB = (char*)Ks + wid * 1024;     // + p*4096

  // ---- V^T staging geometry: tile 128 d x 128 B = 16 KB; 4 passes ----
  const int dVb = tid >> 3;                 // 0..31
  const int cV  = tid & 7;
  const unsigned short* vsrcB = VTh + (size_t)dVb * M_ + (size_t)((cV ^ (dVb & 7)) * 8);
  char* vdstB = (char*)Vt + wid * 1024;     // + p*4096

  // ---- P feed addresses (per-lane, constant across steps) ----
  const int plw0 = (lg >> 1) * 128 + lr * 8 + (lg & 1) * 4;  // pack c at +c*256
  const int plrd = lg * 128 + lr * 8;                         // B-frag kk at +kk*512

#pragma unroll 1
  for (int half = 0; half < 2; ++half) {
    const int ti = half ? (15 - bxw) : bxw;
    const int qblk = ti * 128;              // q-tile base (128 rows)
    const int qrow0 = qblk + wid * 16 + lr; // G0 softmax row
    const int qrow1 = qrow0 + 64;           // G1 softmax row

    // ---- Q fragments for both groups (pre-scaled by log2e/sqrt(D)) ----
    short8 qf0[4], qf1[4];
#pragma unroll
    for (int kk = 0; kk < 4; kk++) {
      qf0[kk] = *(const short8*)&Q[base + (size_t)qrow0 * E_ + kk * 32 + lk8];
      qf1[kk] = *(const short8*)&Q[base + (size_t)qrow1 * E_ + kk * 32 + lk8];
    }

    f32x4 o0[8], o1[8];
#pragma unroll
    for (int d0 = 0; d0 < 8; d0++) {
      o0[d0] = (f32x4){0.f, 0.f, 0.f, 0.f};
      o1[d0] = (f32x4){0.f, 0.f, 0.f, 0.f};
    }
    float m0r = -INFINITY, m1r = -INFINITY;
    float l0 = 0.f, l1 = 0.f;               // per-lane partials (lazy reduce)

    const int nt = 2 * ti + 2;              // steps of 64 kv

    for (int t = 0; t < nt; ++t) {
      const int kv0 = t * 64;
      const size_t koff = (size_t)kv0 * E_;

      // ---- stage K + V^T (8 async global_load_lds; zero staging VALU) ----
#pragma unroll
      for (int p = 0; p < 4; ++p) {
        gld_lds16(ksrcB + koff + (size_t)(16 * p) * E_, kdstB + p * 4096);
        gld_lds16(vsrcB + (size_t)(32 * p) * M_ + kv0,  vdstB + p * 4096);
      }
      __syncthreads();   // barrier drain: tile staged

      const bool g0act = (t < nt - 1);      // G0 done after its diagonal
      const bool mk0   = (t == nt - 2);     // G0 diagonal step
      const bool mk1   = (t == nt - 1);     // G1 diagonal step

      // ---- S^T = K Q^T : shared kf read feeds both groups ----
      f32x4 s0[4], s1[4];
#pragma unroll
      for (int c = 0; c < 4; c++) {
        s0[c] = (f32x4){0.f, 0.f, 0.f, 0.f};
        s1[c] = (f32x4){0.f, 0.f, 0.f, 0.f};
      }
      const int swK = (lr & 7) << 4;
      if (g0act) {
        __builtin_amdgcn_s_setprio(1);
#pragma unroll
        for (int kk = 0; kk < 4; kk++) {
          const int cb = (kk * 64 + lg * 16) ^ swK;
#pragma unroll
          for (int c = 0; c < 4; c++) {
            const short8 kf = *(const short8*)((const char*)Ks + (c * 16 + lr) * 256 + cb);
            s1[c] = __builtin_amdgcn_mfma_f32_16x16x32_bf16(kf, qf1[kk], s1[c], 0, 0, 0);
            s0[c] = __builtin_amdgcn_mfma_f32_16x16x32_bf16(kf, qf0[kk], s0[c], 0, 0, 0);
          }
        }
        __builtin_amdgcn_s_setprio(0);
      } else {
        __builtin_amdgcn_s_setprio(1);
#pragma unroll
        for (int kk = 0; kk < 4; kk++) {
          const int cb = (kk * 64 + lg * 16) ^ swK;
#pragma unroll
          for (int c = 0; c < 4; c++) {
            const short8 kf = *(const short8*)((const char*)Ks + (c * 16 + lr) * 256 + cb);
            s1[c] = __builtin_amdgcn_mfma_f32_16x16x32_bf16(kf, qf1[kk], s1[c], 0, 0, 0);
          }
        }
        __builtin_amdgcn_s_setprio(0);
      }

      // ======== G1 softmax (always active) ========
      {
        float v[4][4];
#pragma unroll
        for (int c = 0; c < 4; c++)
#pragma unroll
          for (int r = 0; r < 4; r++) v[c][r] = s1[c][r];
        if (mk1) {
#pragma unroll
          for (int c = 0; c < 4; c++) {
            const int kvq = kv0 + c * 16 + lg * 4;
#pragma unroll
            for (int r = 0; r < 4; r++)
              if (kvq + r > qrow1) v[c][r] = -INFINITY;
          }
        }
        float pm = fmaxf(fmaxf(fmaxf(v[0][0], v[0][1]), fmaxf(v[0][2], v[0][3])),
                         fmaxf(fmaxf(v[1][0], v[1][1]), fmaxf(v[1][2], v[1][3])));
        pm = fmaxf(pm, fmaxf(fmaxf(fmaxf(v[2][0], v[2][1]), fmaxf(v[2][2], v[2][3])),
                             fmaxf(fmaxf(v[3][0], v[3][1]), fmaxf(v[3][2], v[3][3]))));
        pm = fmaxf(pm, __shfl_xor(pm, 16));
        pm = fmaxf(pm, __shfl_xor(pm, 32));
        const float need = pm - m1r;
        if (!__all(need <= 8.f)) {
          const float mnew = fmaxf(m1r, pm);
          const float al = fexp2(m1r - mnew);
          l1 *= al;
#pragma unroll
          for (int d0 = 0; d0 < 8; ++d0) {
            f32x4 tt = o1[d0];
            tt[0] *= al; tt[1] *= al; tt[2] *= al; tt[3] *= al;
            o1[d0] = tt;
          }
          m1r = mnew;
        }
        ushort4 wpk[4];
        float ps = 0.f;
#pragma unroll
        for (int c = 0; c < 4; c++) {
          const float e0 = fexp2(v[c][0] - m1r);
          const float e1 = fexp2(v[c][1] - m1r);
          const float e2 = fexp2(v[c][2] - m1r);
          const float e3 = fexp2(v[c][3] - m1r);
          wpk[c].x = f2bf(e0); wpk[c].y = f2bf(e1);
          wpk[c].z = f2bf(e2); wpk[c].w = f2bf(e3);
          ps += (e0 + e1) + (e2 + e3);
        }
        l1 += ps;
#pragma unroll
        for (int c = 0; c < 4; c++)
          *(ushort4*)&Plf[1024 + plw0 + c * 256] = wpk[c];
      }

      // ======== G0 softmax (while active) ========
      if (g0act) {
        float v[4][4];
#pragma unroll
        for (int c = 0; c < 4; c++)
#pragma unroll
          for (int r = 0; r < 4; r++) v[c][r] = s0[c][r];
        if (mk0) {
#pragma unroll
          for (int c = 0; c < 4; c++) {
            const int kvq = kv0 + c * 16 + lg * 4;
#pragma unroll
            for (int r = 0; r < 4; r++)
              if (kvq + r > qrow0) v[c][r] = -INFINITY;
          }
        }
        float pm = fmaxf(fmaxf(fmaxf(v[0][0], v[0][1]), fmaxf(v[0][2], v[0][3])),
                         fmaxf(fmaxf(v[1][0], v[1][1]), fmaxf(v[1][2], v[1][3])));
        pm = fmaxf(pm, fmaxf(fmaxf(fmaxf(v[2][0], v[2][1]), fmaxf(v[2][2], v[2][3])),
                             fmaxf(fmaxf(v[3][0], v[3][1]), fmaxf(v[3][2], v[3][3]))));
        pm = fmaxf(pm, __shfl_xor(pm, 16));
        pm = fmaxf(pm, __shfl_xor(pm, 32));
        const float need = pm - m0r;
        if (!__all(need <= 8.f)) {
          const float mnew = fmaxf(m0r, pm);
          const float al = fexp2(m0r - mnew);
          l0 *= al;
#pragma unroll
          for (int d0 = 0; d0 < 8; ++d0) {
            f32x4 tt = o0[d0];
            tt[0] *= al; tt[1] *= al; tt[2] *= al; tt[3] *= al;
            o0[d0] = tt;
          }
          m0r = mnew;
        }
        ushort4 wpk[4];
        float ps = 0.f;
#pragma unroll
        for (int c = 0; c < 4; c++) {
          const float e0 = fexp2(v[c][0] - m0r);
          const float e1 = fexp2(v[c][1] - m0r);
          const float e2 = fexp2(v[c][2] - m0r);
          const float e3 = fexp2(v[c][3] - m0r);
          wpk[c].x = f2bf(e0); wpk[c].y = f2bf(e1);
          wpk[c].z = f2bf(e2); wpk[c].w = f2bf(e3);
          ps += (e0 + e1) + (e2 + e3);
        }
        l0 += ps;
#pragma unroll
        for (int c = 0; c < 4; c++)
          *(ushort4*)&Plf[plw0 + c * 256] = wpk[c];
      }

      // wave-local: drain Pl writes; fence scheduler (rule 18)
      asm volatile("s_waitcnt lgkmcnt(0)" ::: "memory");
      __builtin_amdgcn_sched_barrier(0);

      // ---- O^T += V^T P : shared vb read feeds both groups ----
      const short8 pb1a = *(const short8*)&Plf[1024 + plrd];
      const short8 pb1b = *(const short8*)&Plf[1024 + plrd + 512];
      const int d7 = lr & 7;
      if (g0act) {
        const short8 pb0a = *(const short8*)&Plf[plrd];
        const short8 pb0b = *(const short8*)&Plf[plrd + 512];
        __builtin_amdgcn_s_setprio(1);
#pragma unroll
        for (int d0 = 0; d0 < 8; ++d0) {
          const int d = d0 * 16 + lr;
          const short8 vb0 = *(const short8*)&Vt[d * 64 + ((lg ^ d7) << 3)];
          const short8 vb1 = *(const short8*)&Vt[d * 64 + (((4 + lg) ^ d7) << 3)];
          o1[d0] = __builtin_amdgcn_mfma_f32_16x16x32_bf16(vb0, pb1a, o1[d0], 0, 0, 0);
          o1[d0] = __builtin_amdgcn_mfma_f32_16x16x32_bf16(vb1, pb1b, o1[d0], 0, 0, 0);
          o0[d0] = __builtin_amdgcn_mfma_f32_16x16x32_bf16(vb0, pb0a, o0[d0], 0, 0, 0);
          o0[d0] = __builtin_amdgcn_mfma_f32_16x16x32_bf16(vb1, pb0b, o0[d0], 0, 0, 0);
        }
        __builtin_amdgcn_s_setprio(0);
      } else {
        __builtin_amdgcn_s_setprio(1);
#pragma unroll
        for (int d0 = 0; d0 < 8; ++d0) {
          const int d = d0 * 16 + lr;
          const short8 vb0 = *(const short8*)&Vt[d * 64 + ((lg ^ d7) << 3)];
          const short8 vb1 = *(const short8*)&Vt[d * 64 + (((4 + lg) ^ d7) << 3)];
          o1[d0] = __builtin_amdgcn_mfma_f32_16x16x32_bf16(vb0, pb1a, o1[d0], 0, 0, 0);
          o1[d0] = __builtin_amdgcn_mfma_f32_16x16x32_bf16(vb1, pb1b, o1[d0], 0, 0, 0);
        }
        __builtin_amdgcn_s_setprio(0);
      }
      __syncthreads();   // all Ks/Vt reads done before next staging
    }

    // ---- finalize lsums (lazy reduce) + store ctx for both groups ----
    float ls0 = l0, ls1 = l1;
    ls0 += __shfl_xor(ls0, 16); ls0 += __shfl_xor(ls0, 32);
    ls1 += __shfl_xor(ls1, 16); ls1 += __shfl_xor(ls1, 32);
    const float inv0 = 1.0f / ls0;
    const float inv1 = 1.0f / ls1;
    unsigned short* crow0 = Ctx + base + (size_t)qrow0 * E_ + lg * 4;
    unsigned short* crow1 = Ctx + base + (size_t)qrow1 * E_ + lg * 4;
#pragma unroll
    for (int d0 = 0; d0 < 8; ++d0) {
      ushort4 st0, st1;
      st0.x = f2bf(o0[d0][0] * inv0);
      st0.y = f2bf(o0[d0][1] * inv0);
      st0.z = f2bf(o0[d0][2] * inv0);
      st0.w = f2bf(o0[d0][3] * inv0);
      st1.x = f2bf(o1[d0][0] * inv1);
      st1.y = f2bf(o1[d0][1] * inv1);
      st1.z = f2bf(o1[d0][2] * inv1);
      st1.w = f2bf(o1[d0][3] * inv1);
      *(ushort4*)&crow0[d0 * 16] = st0;
      *(ushort4*)&crow1[d0 * 16] = st1;
    }
  }
}

// ---------------- launcher ----------------
extern "C" void kernel_launch(void* const* d_in, const int* in_sizes, int n_in,
                              void* d_out, int out_size, void* d_ws, size_t ws_size,
                              hipStream_t stream) {
  const float* x  = (const float*)d_in[0];
  // d_in[1] = causal_mask (tril) — implemented analytically
  const float* wq = (const float*)d_in[2];
  const float* bq = (const float*)d_in[3];
  const float* wk = (const float*)d_in[4];
  const float* bk = (const float*)d_in[5];
  const float* wv = (const float*)d_in[6];
  const float* bv = (const float*)d_in[7];
  const float* wo = (const float*)d_in[8];
  const float* bo = (const float*)d_in[9];
  float* out = (float*)d_out;

  char* ws = (char*)d_ws;
  const size_t MB = 1024 * 1024;
  unsigned short* xb  = (unsigned short*)(ws);             // 32 MB
  unsigned short* wqb = (unsigned short*)(ws + 32 * MB);   // 8 MB
  unsigned short* wkb = (unsigned short*)(ws + 40 * MB);   // 8 MB
  unsigned short* wvb = (unsigned short*)(ws + 48 * MB);   // 8 MB
  unsigned short* wob = (unsigned short*)(ws + 56 * MB);   // 8 MB
  unsigned short* Qb  = (unsigned short*)(ws + 64 * MB);   // 32 MB
  unsigned short* Kb  = (unsigned short*)(ws + 96 * MB);   // 32 MB
  unsigned short* VTb = (unsigned short*)(ws + 128 * MB);  // 32 MB, V^T [E][M]
  unsigned short* Cb  = (unsigned short*)(ws + 160 * MB);  // 32 MB -> 192 MB total

  const int nx4 = M_ * E_ / 4;   // x elements /4
  const int nw4 = E_ * E_ / 4;   // weight elements /4
  cast_bf16_kernel<<<nx4 / 256, 256, 0, stream>>>(x, xb, nx4);
  cast_w4_kernel<<<dim3(nw4 / 256, 4), 256, 0, stream>>>(wq, wk, wv, wo,
                                                         wqb, wkb, wvb, wob, nw4);

  // Q pre-scale: log2(e)/sqrt(D) -> attention works in log2-space (exp2 softmax)
  const float scale = 0.08838834764831845f * 1.44269504088896340736f;

  // fused Q/K/V projections, y-decoded: 256 x 3 blocks; per-GEMM standalone
  // swizzle locality + no inter-launch drain
  gemm_qkv<<<dim3(256, 3), 512, 0, stream>>>(xb, wqb, wkb, wvb, bq, bk, bv,
                                             Qb, Kb, VTb, M_, E_, E_, scale);

  // folded causal grid: block handles 128-row q-tiles bxw and 15-bxw (34 steps)
  flash_attn<<<dim3(S_ / 128 / 2, H_, B_), 256, 0, stream>>>(Qb, Kb, VTb, Cb);

  // O-projection
  gemm_bt256<float><<<dim3(E_ / 256, M_ / 256), 512, 0, stream>>>(Cb, wob, bo, out, M_, E_, E_, 1.0f);
}